// Round 5
// baseline (98.621 us; speedup 1.0000x reference)
//
#include <hip/hip_runtime.h>
#include <math.h>

#define BB 64
#define DD 512
#define HH 8
#define EPS 1e-8f
#define NCH 8          // chunks per jc-half
#define CS 32          // j's per chunk (NCH*CS = 256)

// Raw v_rcp_f32 (~1 ulp). Used identically for the softmax max (m) and the
// per-j r, so r-m cancels exactly at the argmin (same instruction, same input).
__device__ __forceinline__ float fast_rcp(float d) {
    return __builtin_amdgcn_rcpf(d);
}

// Kernel A: rank-sort each row of x. Sorted order groups lanes with adjacent
// attention centers p_i so per-wave softmax windows overlap (enables chunk skip).
__global__ __launch_bounds__(512) void sort_rows(
    const float* __restrict__ x,
    float* __restrict__ xsorted,
    unsigned short* __restrict__ isorted)
{
    const int b = blockIdx.x;
    const int i = threadIdx.x;
    __shared__ float sx[DD];
    const float xi = x[b * DD + i];
    sx[i] = xi;
    __syncthreads();
    int rank = 0;
    for (int j = 0; j < DD; j += 4) {
        float4 v = *(const float4*)&sx[j];
        rank += (v.x < xi) | ((v.x == xi) & ((j + 0) < i));
        rank += (v.y < xi) | ((v.y == xi) & ((j + 1) < i));
        rank += (v.z < xi) | ((v.z == xi) & ((j + 2) < i));
        rank += (v.w < xi) | ((v.w == xi) & ((j + 3) < i));
    }
    xsorted[b * DD + rank] = xi;
    isorted[b * DD + rank] = (unsigned short)i;
}

// Kernel B: block = 512 threads: (ii, jc) = (tid & 255, tid >> 8).
// Lanes take i in sorted-x order; pass 2 skips 32-j chunks whose max possible
// softmax weight is < 2^-40 for every lane in the wave (exact-result pruning).
__global__ __launch_bounds__(512, 8) void flattn_kernel(
    const float* __restrict__ xsorted,
    const unsigned short* __restrict__ isorted,
    const float* __restrict__ alphas,
    const float* __restrict__ betas,
    float* __restrict__ out)
{
    const int b  = blockIdx.x;     // batch
    const int ic = blockIdx.y;     // i-chunk (0..1)
    const int h  = blockIdx.z;     // head

    __shared__ float xs[DD];
    __shared__ float mind_sh[2][256];
    __shared__ float ss_sh[256];
    __shared__ float sx_sh[256];

    const int tid = threadIdx.x;
    const int ii  = tid & 255;
    const int jc  = tid >> 8;          // wave-uniform
    const int i   = ic * 256 + ii;     // sorted slot

    const float a0 = alphas[h * 3 + 0];
    const float a1 = alphas[h * 3 + 1];
    const float a2 = alphas[h * 3 + 2];
    const float b0 = betas[h * 3 + 0];
    const float b1 = betas[h * 3 + 1];
    const float b2 = betas[h * 3 + 2];

    xs[tid] = xsorted[b * DD + tid];
    __syncthreads();

    const float xi = xs[i];
    const float c  = b0 - fmaf(a1, xi, b1);   // q_j - k_i = a0*x_j + c
    const int j0 = jc * 256;

    // Pass 1: per-chunk mins + global min (fma + min(abs) = 2 VALU/j).
    float cmin[NCH];
    float gmin = 3.0e38f;
    #pragma unroll
    for (int ch = 0; ch < NCH; ++ch) {
        const int base = j0 + ch * CS;
        float cm = 3.0e38f;
        #pragma unroll
        for (int jj = 0; jj < CS; jj += 4) {
            float4 x4 = *(const float4*)&xs[base + jj];
            cm = fminf(cm, fabsf(fmaf(a0, x4.x, c)));
            cm = fminf(cm, fabsf(fmaf(a0, x4.y, c)));
            cm = fminf(cm, fabsf(fmaf(a0, x4.z, c)));
            cm = fminf(cm, fabsf(fmaf(a0, x4.w, c)));
        }
        cmin[ch] = cm;
        gmin = fminf(gmin, cm);
    }
    mind_sh[jc][ii] = gmin;
    __syncthreads();

    gmin = fminf(mind_sh[0][ii], mind_sh[1][ii]);
    const float m = fast_rcp(gmin + EPS);      // same expr as pass 2's r
    const float log2e = 1.4426950408889634f;
    const float negml = -m * log2e;
    // Keep chunk iff some lane has cmin <= thr, thr = 1/(m-28):
    // skipped terms have exp2-arg < -28*log2e ~ -40  ->  s < 2^-40 (negligible).
    const float mr = m - 28.0f;
    const float thr = (mr > 0.0f) ? fast_rcp(mr) : 3.0e38f;

    // Pass 2: softmax-weighted sums over kept chunks only.
    float ss = 0.0f, sx = 0.0f;
    #pragma unroll
    for (int ch = 0; ch < NCH; ++ch) {
        if (__ballot(cmin[ch] <= thr)) {       // wave-uniform skip
            const int base = j0 + ch * CS;
            #pragma unroll 4
            for (int jj = 0; jj < CS; jj += 4) {
                float4 x4 = *(const float4*)&xs[base + jj];
                {
                    float t = fmaf(a0, x4.x, c);
                    float r = fast_rcp(fabsf(t) + EPS);
                    float s = __builtin_amdgcn_exp2f(fmaf(r, log2e, negml));
                    ss += s; sx = fmaf(s, x4.x, sx);
                }
                {
                    float t = fmaf(a0, x4.y, c);
                    float r = fast_rcp(fabsf(t) + EPS);
                    float s = __builtin_amdgcn_exp2f(fmaf(r, log2e, negml));
                    ss += s; sx = fmaf(s, x4.y, sx);
                }
                {
                    float t = fmaf(a0, x4.z, c);
                    float r = fast_rcp(fabsf(t) + EPS);
                    float s = __builtin_amdgcn_exp2f(fmaf(r, log2e, negml));
                    ss += s; sx = fmaf(s, x4.z, sx);
                }
                {
                    float t = fmaf(a0, x4.w, c);
                    float r = fast_rcp(fabsf(t) + EPS);
                    float s = __builtin_amdgcn_exp2f(fmaf(r, log2e, negml));
                    ss += s; sx = fmaf(s, x4.w, sx);
                }
            }
        }
    }

    // Merge the two jc-halves via LDS, then one atomic per (i, h).
    if (jc == 1) { ss_sh[ii] = ss; sx_sh[ii] = sx; }
    __syncthreads();
    if (jc == 0) {
        ss += ss_sh[ii];
        sx += sx_sh[ii];
        const float scale = 0.04419417382415922f;   // 1/sqrt(512)
        float sv  = fmaf(a2, sx, b2 * ss);
        float att = sv * fast_rcp(ss) * scale;
        if (h == 0) att += xi;
        const int oi = (int)isorted[b * DD + i];    // original position
        atomicAdd(&out[b * DD + oi], att);
    }
}

extern "C" void kernel_launch(void* const* d_in, const int* in_sizes, int n_in,
                              void* d_out, int out_size, void* d_ws, size_t ws_size,
                              hipStream_t stream) {
    const float* x      = (const float*)d_in[0];
    const float* alphas = (const float*)d_in[1];
    const float* betas  = (const float*)d_in[2];
    float* out = (float*)d_out;

    float* xsorted = (float*)d_ws;                          // 64*512*4   = 128 KB
    unsigned short* isorted = (unsigned short*)(xsorted + BB * DD);  // +64 KB

    hipMemsetAsync(out, 0, (size_t)out_size * sizeof(float), stream);

    sort_rows<<<dim3(BB), dim3(DD), 0, stream>>>(x, xsorted, isorted);

    dim3 grid(BB, 2, HH);
    dim3 block(512);
    flattn_kernel<<<grid, block, 0, stream>>>(xsorted, isorted, alphas, betas, out);
}

// Round 6
// 94.416 us; speedup vs baseline: 1.0445x; 1.0445x over previous
//
#include <hip/hip_runtime.h>
#include <math.h>
#include <stdint.h>

#define BB 64
#define DD 512
#define HH 8
#define EPS 1e-8f
#define NCH 8          // chunks per jc-half
#define CS 32          // j's per chunk (NCH*CS = 256)

// Raw v_rcp_f32 (~1 ulp). Used identically for the softmax max (m) and the
// per-j r, so r-m cancels exactly at the argmin (same instruction, same input).
__device__ __forceinline__ float fast_rcp(float d) {
    return __builtin_amdgcn_rcpf(d);
}

// One block per (b, h), 1024 threads: (ii, jc) = (tid & 511, tid >> 9).
// The block rank-sorts its x-row in LDS (no global scratch -> no d_ws poison
// tax), takes i in sorted order so each wave's 64 lanes have adjacent
// attention centers, then prunes 32-j chunks whose max possible softmax
// weight is < 2^-40 for every lane in the wave (exact-result pruning).
__global__ __launch_bounds__(1024, 8) void flattn_kernel(
    const float* __restrict__ x,
    const float* __restrict__ alphas,
    const float* __restrict__ betas,
    float* __restrict__ out)
{
    const int b = blockIdx.x;
    const int h = blockIdx.y;

    __shared__ uint64_t keys[DD];        // sortable key || index
    __shared__ float    xs[DD];          // sorted row values
    __shared__ int      idxs[DD];        // sorted slot -> original index
    __shared__ int      cnt[2][DD];      // partial ranks
    __shared__ float    mind_sh[2][DD];
    __shared__ float    ss_sh[DD];
    __shared__ float    sx_sh[DD];

    const int tid = threadIdx.x;
    const int ii  = tid & (DD - 1);
    const int jc  = tid >> 9;            // wave-uniform (waves 0-7 -> 0, 8-15 -> 1)
    const int j0  = jc * 256;

    // --- rank-sort the row in LDS ---
    const float xv = x[b * DD + ii];
    if (jc == 0) {
        uint32_t u = __float_as_uint(xv);
        uint32_t k = (u & 0x80000000u) ? ~u : (u | 0x80000000u);  // monotone map
        keys[ii] = ((uint64_t)k << 16) | (uint32_t)ii;            // tie-safe
    }
    __syncthreads();

    const uint64_t myk = keys[ii];
    int rk = 0;
    #pragma unroll 8
    for (int j = j0; j < j0 + 256; j += 2) {
        rk += (keys[j]     < myk);
        rk += (keys[j + 1] < myk);
    }
    cnt[jc][ii] = rk;
    __syncthreads();
    if (jc == 0) {
        const int rank = cnt[0][ii] + cnt[1][ii];
        xs[rank]   = xv;
        idxs[rank] = ii;
    }
    __syncthreads();

    const float a0 = alphas[h * 3 + 0];
    const float a1 = alphas[h * 3 + 1];
    const float a2 = alphas[h * 3 + 2];
    const float b0 = betas[h * 3 + 0];
    const float b1 = betas[h * 3 + 1];
    const float b2 = betas[h * 3 + 2];

    const float xi = xs[ii];                  // value at sorted slot ii
    const float c  = b0 - fmaf(a1, xi, b1);   // q_j - k_i = a0*x_j + c

    // Pass 1: per-chunk mins + global min (fma,fma,min3 = 1.5 instr/j).
    float cmin[NCH];
    float gmin = 3.0e38f;
    #pragma unroll
    for (int ch = 0; ch < NCH; ++ch) {
        const int base = j0 + ch * CS;
        float cm = 3.0e38f;
        #pragma unroll
        for (int jj = 0; jj < CS; jj += 4) {
            float4 x4 = *(const float4*)&xs[base + jj];
            float ta = fmaf(a0, x4.x, c), tb = fmaf(a0, x4.y, c);
            float tc = fmaf(a0, x4.z, c), td = fmaf(a0, x4.w, c);
            cm = fminf(cm, fminf(fabsf(ta), fabsf(tb)));   // v_min3
            cm = fminf(cm, fminf(fabsf(tc), fabsf(td)));
        }
        cmin[ch] = cm;
        gmin = fminf(gmin, cm);
    }
    mind_sh[jc][ii] = gmin;
    __syncthreads();

    gmin = fminf(mind_sh[0][ii], mind_sh[1][ii]);
    const float m = fast_rcp(gmin + EPS);      // same expr as pass 2's r
    const float log2e = 1.4426950408889634f;
    const float negml = -m * log2e;
    // Keep chunk iff some lane has cmin <= thr, thr = 1/(m-28):
    // skipped terms have exp-arg < -28 -> s < 2^-40 (negligible vs s_max=1).
    const float mr = m - 28.0f;
    const float thr = (mr > 0.0f) ? fast_rcp(mr) : 3.0e38f;

    // Pass 2: softmax-weighted sums over kept chunks only.
    float ss = 0.0f, sx = 0.0f;
    #pragma unroll
    for (int ch = 0; ch < NCH; ++ch) {
        if (__ballot(cmin[ch] <= thr)) {       // wave-uniform skip
            const int base = j0 + ch * CS;
            #pragma unroll 4
            for (int jj = 0; jj < CS; jj += 4) {
                float4 x4 = *(const float4*)&xs[base + jj];
                {
                    float t = fmaf(a0, x4.x, c);
                    float r = fast_rcp(fabsf(t) + EPS);
                    float s = __builtin_amdgcn_exp2f(fmaf(r, log2e, negml));
                    ss += s; sx = fmaf(s, x4.x, sx);
                }
                {
                    float t = fmaf(a0, x4.y, c);
                    float r = fast_rcp(fabsf(t) + EPS);
                    float s = __builtin_amdgcn_exp2f(fmaf(r, log2e, negml));
                    ss += s; sx = fmaf(s, x4.y, sx);
                }
                {
                    float t = fmaf(a0, x4.z, c);
                    float r = fast_rcp(fabsf(t) + EPS);
                    float s = __builtin_amdgcn_exp2f(fmaf(r, log2e, negml));
                    ss += s; sx = fmaf(s, x4.z, sx);
                }
                {
                    float t = fmaf(a0, x4.w, c);
                    float r = fast_rcp(fabsf(t) + EPS);
                    float s = __builtin_amdgcn_exp2f(fmaf(r, log2e, negml));
                    ss += s; sx = fmaf(s, x4.w, sx);
                }
            }
        }
    }

    // Merge the two jc-halves via LDS, then one atomic per (i, h).
    if (jc == 1) { ss_sh[ii] = ss; sx_sh[ii] = sx; }
    __syncthreads();
    if (jc == 0) {
        ss += ss_sh[ii];
        sx += sx_sh[ii];
        const float scale = 0.04419417382415922f;   // 1/sqrt(512)
        float sv  = fmaf(a2, sx, b2 * ss);          // vs[] folded: a2*sx + b2*ss
        float att = sv * fast_rcp(ss) * scale;
        if (h == 0) att += xi;
        atomicAdd(&out[b * DD + idxs[ii]], att);    // scatter to original pos
    }
}

extern "C" void kernel_launch(void* const* d_in, const int* in_sizes, int n_in,
                              void* d_out, int out_size, void* d_ws, size_t ws_size,
                              hipStream_t stream) {
    const float* x      = (const float*)d_in[0];
    const float* alphas = (const float*)d_in[1];
    const float* betas  = (const float*)d_in[2];
    float* out = (float*)d_out;

    hipMemsetAsync(out, 0, (size_t)out_size * sizeof(float), stream);

    dim3 grid(BB, HH);
    dim3 block(1024);
    flattn_kernel<<<grid, block, 0, stream>>>(x, alphas, betas, out);
}

// Round 7
// 93.564 us; speedup vs baseline: 1.0541x; 1.0091x over previous
//
#include <hip/hip_runtime.h>
#include <math.h>
#include <stdint.h>

#define BB 64
#define DD 512
#define HH 8
#define EPS 1e-8f

// Raw v_rcp_f32 (~1 ulp). Used identically for the softmax max (m) and the
// per-j r, so r-m cancels exactly at the argmin (same instruction, same input).
__device__ __forceinline__ float fast_rcp(float d) {
    return __builtin_amdgcn_rcpf(d);
}

// One block per (b, 64-wide sorted-i window). 1024 threads = (ii,jc) =
// (tid&63, tid>>6): wave = 64 adjacent sorted i's x one 32-j chunk.
// Every thread processes ALL 8 heads (2 groups of 4) -> every block has
// identical work -> no cross-block load imbalance from dense heads.
// Chunk pruning: skip a (wave, head, chunk) iff no lane's min-dist can give
// softmax weight >= 2^-40 (exact-result pruning). All 8 heads of each (b,i)
// finish in-block -> single plain store, no memset/atomics.
__global__ __launch_bounds__(1024, 8) void flattn_kernel(
    const float* __restrict__ x,
    const float* __restrict__ alphas,
    const float* __restrict__ betas,
    float* __restrict__ out)
{
    const int b  = blockIdx.x;
    const int ic = blockIdx.y;            // sorted-i window [ic*64, ic*64+64)

    __shared__ float xs[DD];              // sorted row
    __shared__ int   idxs[DD];            // sorted slot -> original index
    __shared__ float attp[HH][64];        // per-head attended, this i-window
    __shared__ union {
        struct { uint64_t keys[DD]; int cnt[2][DD]; } s;                 // 8 KB
        struct { float pmin[4][16][64], pss[4][16][64], psx[4][16][64]; } g; // 48 KB
    } u;

    const int tid = threadIdx.x;

    // ---- rank-sort the row in LDS (2 threads per key count 256 each) ----
    const int si = tid & (DD - 1);
    const int sg = tid >> 9;
    const float xv = x[b * DD + si];
    if (sg == 0) {
        uint32_t w = __float_as_uint(xv);
        uint32_t k = (w & 0x80000000u) ? ~w : (w | 0x80000000u);  // monotone map
        u.s.keys[si] = ((uint64_t)k << 32) | (uint32_t)si;        // tie-safe
    }
    __syncthreads();
    {
        const uint64_t myk = u.s.keys[si];
        const int jb = sg * 256;
        int rk = 0;
        #pragma unroll 8
        for (int j = jb; j < jb + 256; j += 2) {
            rk += (u.s.keys[j]     < myk);
            rk += (u.s.keys[j + 1] < myk);
        }
        u.s.cnt[sg][si] = rk;
    }
    __syncthreads();
    if (sg == 0) {
        const int rank = u.s.cnt[0][si] + u.s.cnt[1][si];
        xs[rank]   = xv;
        idxs[rank] = si;
    }
    __syncthreads();

    const int ii = tid & 63;
    const int jc = tid >> 6;              // 0..15, wave-uniform
    const int i  = ic * 64 + ii;
    const int jb = jc * 32;
    const float xi = xs[i];

    const float scale = 0.04419417382415922f;   // 1/sqrt(512)
    const float log2e = 1.4426950408889634f;

    for (int gset = 0; gset < 2; ++gset) {
        float a0v[4], c[4], cm[4];
        #pragma unroll
        for (int hh = 0; hh < 4; ++hh) {
            const int h = gset * 4 + hh;
            a0v[hh] = alphas[h * 3 + 0];
            const float a1 = alphas[h * 3 + 1];
            c[hh]  = betas[h * 3 + 0] - fmaf(a1, xi, betas[h * 3 + 1]);
            cm[hh] = 3.0e38f;
        }

        // Pass 1: this thread's 32-j chunk min for 4 heads (fma+min(abs)).
        #pragma unroll
        for (int jj = 0; jj < 32; jj += 4) {
            float4 x4 = *(const float4*)&xs[jb + jj];
            #pragma unroll
            for (int hh = 0; hh < 4; ++hh) {
                float ta = fmaf(a0v[hh], x4.x, c[hh]), tb = fmaf(a0v[hh], x4.y, c[hh]);
                float tc = fmaf(a0v[hh], x4.z, c[hh]), td = fmaf(a0v[hh], x4.w, c[hh]);
                cm[hh] = fminf(cm[hh], fminf(fabsf(ta), fabsf(tb)));
                cm[hh] = fminf(cm[hh], fminf(fabsf(tc), fabsf(td)));
            }
        }
        #pragma unroll
        for (int hh = 0; hh < 4; ++hh) u.g.pmin[hh][jc][ii] = cm[hh];
        __syncthreads();

        // Global min per (i,h) -> m, thr; pass 2 over kept chunks.
        float ssv[4], sxv[4];
        #pragma unroll
        for (int hh = 0; hh < 4; ++hh) {
            float gm = 3.0e38f;
            #pragma unroll
            for (int k = 0; k < 16; ++k) gm = fminf(gm, u.g.pmin[hh][k][ii]);
            const float m = fast_rcp(gm + EPS);     // same expr as pass 2's r
            const float negml = -m * log2e;
            const float mr = m - 28.0f;
            // skipped terms have exp-arg < -28 -> s < 2^-40 (negligible vs 1)
            const float thr = (mr > 0.0f) ? fast_rcp(mr) : 3.0e38f;

            float ss = 0.0f, sx = 0.0f;
            if (__ballot(cm[hh] <= thr)) {          // wave-uniform chunk skip
                const float a0 = a0v[hh], cc = c[hh];
                #pragma unroll
                for (int jj = 0; jj < 32; jj += 4) {
                    float4 x4 = *(const float4*)&xs[jb + jj];
                    {
                        float t = fmaf(a0, x4.x, cc);
                        float r = fast_rcp(fabsf(t) + EPS);
                        float s = __builtin_amdgcn_exp2f(fmaf(r, log2e, negml));
                        ss += s; sx = fmaf(s, x4.x, sx);
                    }
                    {
                        float t = fmaf(a0, x4.y, cc);
                        float r = fast_rcp(fabsf(t) + EPS);
                        float s = __builtin_amdgcn_exp2f(fmaf(r, log2e, negml));
                        ss += s; sx = fmaf(s, x4.y, sx);
                    }
                    {
                        float t = fmaf(a0, x4.z, cc);
                        float r = fast_rcp(fabsf(t) + EPS);
                        float s = __builtin_amdgcn_exp2f(fmaf(r, log2e, negml));
                        ss += s; sx = fmaf(s, x4.z, sx);
                    }
                    {
                        float t = fmaf(a0, x4.w, cc);
                        float r = fast_rcp(fabsf(t) + EPS);
                        float s = __builtin_amdgcn_exp2f(fmaf(r, log2e, negml));
                        ss += s; sx = fmaf(s, x4.w, sx);
                    }
                }
            }
            ssv[hh] = ss; sxv[hh] = sx;             // zeros if skipped
        }
        #pragma unroll
        for (int hh = 0; hh < 4; ++hh) {
            u.g.pss[hh][jc][ii] = ssv[hh];
            u.g.psx[hh][jc][ii] = sxv[hh];
        }
        __syncthreads();

        // Merge over jc: waves 0..3 each handle one head of this group.
        if (jc < 4) {
            const int hh = jc;
            const int h  = gset * 4 + hh;
            float ss = 0.0f, sx = 0.0f;
            #pragma unroll
            for (int k = 0; k < 16; ++k) {
                ss += u.g.pss[hh][k][ii];
                sx += u.g.psx[hh][k][ii];
            }
            const float a2 = alphas[h * 3 + 2];
            const float b2 = betas[h * 3 + 2];
            float sv = fmaf(a2, sx, b2 * ss);       // vs[] folded out
            attp[h][ii] = sv * fast_rcp(ss) * scale;
        }
        __syncthreads();
    }

    // Final: one plain store per (b, i) — all heads computed in this block.
    if (tid < 64) {
        float acc = xs[ic * 64 + tid];              // residual x
        #pragma unroll
        for (int h = 0; h < HH; ++h) acc += attp[h][tid];
        out[b * DD + idxs[ic * 64 + tid]] = acc;
    }
}

extern "C" void kernel_launch(void* const* d_in, const int* in_sizes, int n_in,
                              void* d_out, int out_size, void* d_ws, size_t ws_size,
                              hipStream_t stream) {
    const float* x      = (const float*)d_in[0];
    const float* alphas = (const float*)d_in[1];
    const float* betas  = (const float*)d_in[2];
    float* out = (float*)d_out;

    dim3 grid(BB, DD / 64);   // 64 x 8 = 512 blocks, all identical work
    dim3 block(1024);
    flattn_kernel<<<grid, block, 0, stream>>>(x, alphas, betas, out);
}